// Round 4
// baseline (1028.800 us; speedup 1.0000x reference)
//
#include <hip/hip_runtime.h>

// GRU_43387759624777 — Round 4: 2 independent blocks per CU to hide phase stalls.
//
// R3 post-mortem: 1932 cyc/step/CU; MfmaUtil 15.8%, VALUBusy 34.5%, conflicts
// ~14%, remainder ~40% stall — 1 block/CU, 2 barriers/step, all phase latency
// (MFMA, LDS round-trip, exp chains) exposed. Fix: 512 blocks x 128 threads
// (2 waves) x 8 rows -> 2 co-resident blocks/CU; block B issues while block A
// is in a barrier. MFMA M=16 tile half-used (rows 8..15 zero) — acceptable,
// MFMA pipe was 84% idle. All verified fragment mappings from R3 unchanged.
//
// Maps (verified m89/m120 + R3 absmax~0): A/B-frag: [dim0=lane&15][k=(lane>>4)*8+j];
// C/D: col=lane&15, row=(lane>>4)*4+reg. Split-bf16: Whi*hhi + Whi*hlo + Wlo*hhi.

#define HID 64
#define SEQ 1024
#define BATCH 4096
#define ROWS 8
#define THREADS 128
#define NTW 6   // N-tiles per wave (12 tiles / 2 waves)

typedef __attribute__((ext_vector_type(8))) short short8;
typedef __attribute__((ext_vector_type(4))) float f32x4;

__device__ __forceinline__ short f2bf(float f) {
  unsigned u = __float_as_uint(f);
  u += 0x7fffu + ((u >> 16) & 1u);   // RNE
  return (short)(u >> 16);
}
__device__ __forceinline__ float bf2f(short s) {
  return __uint_as_float(((unsigned)(unsigned short)s) << 16);
}
__device__ __forceinline__ float rcp_fast(float x) { return __builtin_amdgcn_rcpf(x); }

__global__ __launch_bounds__(THREADS, 1) void gru_mfma(
    const float* __restrict__ x,     // [B, T]
    const float* __restrict__ w_ih,  // [192, 1]
    const float* __restrict__ w_hh,  // [192, 64]
    const float* __restrict__ b_ih,  // [192]
    const float* __restrict__ b_hh,  // [192]
    const float* __restrict__ w1,    // [32, 64]
    const float* __restrict__ b1,    // [32]
    const float* __restrict__ w2,    // [16, 32]
    const float* __restrict__ b2,    // [16]
    const float* __restrict__ w3,    // [1, 16]
    const float* __restrict__ b3,    // [1]
    float* __restrict__ out)         // [B, 1]
{
  const int L  = threadIdx.x;        // 0..127
  const int l  = L & 63;             // lane in wave
  const int wv = L >> 6;             // wave 0..1
  const int r0 = blockIdx.x * ROWS;  // first batch row of this block

  // ---------------- LDS ----------------
  __shared__ __align__(16) short hfrag[2][2][64][8]; // [hi/lo][kt][lane][j] bf16 A-frags (4 KB)
  __shared__ float gbuf[3][ROWS][68];                // [gate][row][unit] fp32 gate pre-acts
  __shared__ float xbuf[ROWS][68];                   // 64-step x chunk (reused for h at end)
  __shared__ float ybuf1[ROWS][36];
  __shared__ float ybuf2[ROWS][20];

  // ---------------- W fragments (registers, once) ----------------
  // B-frag for tile nt, kt: lane holds w_hh[nt*16 + (l&15)][kt*32 + (l>>4)*8 + j]
  short8 bhi[NTW][2], blo[NTW][2];
  {
    const int n0 = l & 15, q = l >> 4;
    #pragma unroll
    for (int nt3 = 0; nt3 < NTW; ++nt3) {
      const int c = (wv * NTW + nt3) * 16 + n0;
      #pragma unroll
      for (int kt = 0; kt < 2; ++kt) {
        const float* p = w_hh + c * HID + kt * 32 + q * 8;
        f32x4 p0 = *(const f32x4*)p;
        f32x4 p1 = *(const f32x4*)(p + 4);
        float vals[8] = {p0[0], p0[1], p0[2], p0[3], p1[0], p1[1], p1[2], p1[3]};
        short8 hi8, lo8;
        #pragma unroll
        for (int j = 0; j < 8; ++j) {
          short h8 = f2bf(vals[j]);
          hi8[j] = h8;
          lo8[j] = f2bf(vals[j] - bf2f(h8));
        }
        bhi[nt3][kt] = hi8;
        blo[nt3][kt] = lo8;
      }
    }
  }

  // ---------------- per-lane elementwise constants ----------------
  // Lane (m = L>>4 in 0..7, g = L&15) owns units u = 4g..4g+3 of row m.
  const int m = L >> 4;
  const int g = L & 15;
  float wir[4], wiz[4], win[4], br[4], bz[4], bni[4], bnh[4], h[4];
  #pragma unroll
  for (int i = 0; i < 4; ++i) {
    const int u = 4 * g + i;
    wir[i] = w_ih[u]; wiz[i] = w_ih[64 + u]; win[i] = w_ih[128 + u];
    br[i]  = b_ih[u] + b_hh[u];
    bz[i]  = b_ih[64 + u] + b_hh[64 + u];
    bni[i] = b_ih[128 + u];
    bnh[i] = b_hh[128 + u];
    h[i]   = 0.0f;
  }

  // hfrag write target (rows 8..15 of the A-tile never written -> stay zero):
  // u=4g+i -> kt=g>>3, quad=(g>>1)&3, j=4(g&1)+i, dest lane = m+16*quad
  short* hdst = &hfrag[0][g >> 3][m + 16 * ((g >> 1) & 3)][4 * (g & 1)];
  short* ldst = &hfrag[1][g >> 3][m + 16 * ((g >> 1) & 3)][4 * (g & 1)];

  // zero-init hfrag (h0 = 0; also zeroes the unused A-rows 8..15)
  for (int i = L; i < 2 * 2 * 64 * 8 / 2; i += THREADS) ((unsigned*)hfrag)[i] = 0u;

  const float* xblk = x + (size_t)r0 * SEQ;

  // ---------------- scan ----------------
  for (int tb = 0; tb < SEQ / 64; ++tb) {
    __syncthreads();  // xbuf safe to overwrite
    {
      const int row = L >> 4, tq = L & 15;   // 8 rows x 16 quads = 128 threads
      f32x4 v = *(const f32x4*)(xblk + (size_t)row * SEQ + tb * 64 + tq * 4);
      *(f32x4*)&xbuf[row][tq * 4] = v;
    }
    for (int s = 0; s < 64; ++s) {
      __syncthreads();  // hfrag (and xbuf) ready

      // ---- MFMA phase: gh = [hhi+hlo] @ [Whi+Wlo]^T (3 terms) ----
      short8 ahi0 = *(const short8*)&hfrag[0][0][l][0];
      short8 ahi1 = *(const short8*)&hfrag[0][1][l][0];
      short8 alo0 = *(const short8*)&hfrag[1][0][l][0];
      short8 alo1 = *(const short8*)&hfrag[1][1][l][0];
      #pragma unroll
      for (int nt3 = 0; nt3 < NTW; ++nt3) {
        f32x4 a = {0.f, 0.f, 0.f, 0.f};
        a = __builtin_amdgcn_mfma_f32_16x16x32_bf16(ahi0, bhi[nt3][0], a, 0, 0, 0);
        a = __builtin_amdgcn_mfma_f32_16x16x32_bf16(ahi1, bhi[nt3][1], a, 0, 0, 0);
        a = __builtin_amdgcn_mfma_f32_16x16x32_bf16(alo0, bhi[nt3][0], a, 0, 0, 0);
        a = __builtin_amdgcn_mfma_f32_16x16x32_bf16(alo1, bhi[nt3][1], a, 0, 0, 0);
        a = __builtin_amdgcn_mfma_f32_16x16x32_bf16(ahi0, blo[nt3][0], a, 0, 0, 0);
        a = __builtin_amdgcn_mfma_f32_16x16x32_bf16(ahi1, blo[nt3][1], a, 0, 0, 0);
        const int ntg  = wv * NTW + nt3;
        const int gate = ntg >> 2;                    // uniform per tile
        const int u    = ((ntg & 3) << 4) + (l & 15); // col within gate
        if (l < 32) {                                 // D rows 0..7 only (q=0,1)
          #pragma unroll
          for (int r = 0; r < 4; ++r)
            gbuf[gate][(l >> 4) * 4 + r][u] = a[r];
        }
      }
      __syncthreads();  // gbuf ready; hfrag reads done

      // ---- elementwise phase: gates + h update (h stays in registers) ----
      const float xt = xbuf[m][s];
      f32x4 gr4 = *(const f32x4*)&gbuf[0][m][4 * g];
      f32x4 gz4 = *(const f32x4*)&gbuf[1][m][4 * g];
      f32x4 gn4 = *(const f32x4*)&gbuf[2][m][4 * g];
      unsigned hp[2], lp[2];
      #pragma unroll
      for (int i = 0; i < 4; ++i) {
        float rpre = gr4[i] + __fmaf_rn(xt, wir[i], br[i]);
        float r    = rcp_fast(1.0f + __expf(-rpre));
        float zpre = gz4[i] + __fmaf_rn(xt, wiz[i], bz[i]);
        float z    = rcp_fast(1.0f + __expf(-zpre));
        float npre = __fmaf_rn(r, gn4[i] + bnh[i], __fmaf_rn(xt, win[i], bni[i]));
        float n    = 1.0f - 2.0f * rcp_fast(__expf(2.0f * npre) + 1.0f);
        h[i] = __fmaf_rn(z, h[i] - n, n);
        short hi = f2bf(h[i]);
        short lo = f2bf(h[i] - bf2f(hi));
        ((unsigned short*)hp)[i] = (unsigned short)hi;
        ((unsigned short*)lp)[i] = (unsigned short)lo;
      }
      *(uint2*)hdst = make_uint2(hp[0], hp[1]);
      *(uint2*)ldst = make_uint2(lp[0], lp[1]);
    }
  }

  // ---------------- MLP head: 64 -> 32 -> 16 -> 1 ----------------
  __syncthreads();
  *(f32x4*)&xbuf[m][4 * g] = (f32x4){h[0], h[1], h[2], h[3]};  // h fp32 -> LDS
  __syncthreads();

  #pragma unroll
  for (int rep = 0; rep < 2; ++rep) {           // 8 rows x 32 outs = 256 tasks
    const int o = (L & 15) + 16 * rep;
    const int row = L >> 4;
    float a = b1[o];
    #pragma unroll
    for (int j4 = 0; j4 < 16; ++j4) {
      f32x4 wv4 = *(const f32x4*)&w1[o * 64 + 4 * j4];
      f32x4 hv  = *(const f32x4*)&xbuf[row][4 * j4];
      a += wv4[0] * hv[0] + wv4[1] * hv[1] + wv4[2] * hv[2] + wv4[3] * hv[3];
    }
    ybuf1[row][o] = (a > 0.0f) ? a : 0.01f * a;
  }
  __syncthreads();

  {
    const int o = L & 15;                        // 8 rows x 16 outs = 128 tasks
    const int row = L >> 4;
    float a = b2[o];
    #pragma unroll
    for (int j4 = 0; j4 < 8; ++j4) {
      f32x4 wv4 = *(const f32x4*)&w2[o * 32 + 4 * j4];
      f32x4 yv  = *(const f32x4*)&ybuf1[row][4 * j4];
      a += wv4[0] * yv[0] + wv4[1] * yv[1] + wv4[2] * yv[2] + wv4[3] * yv[3];
    }
    ybuf2[row][o] = (a > 0.0f) ? a : 0.01f * a;
  }
  __syncthreads();

  if (L < ROWS) {
    float a = b3[0];
    #pragma unroll
    for (int j = 0; j < 16; ++j) a = __fmaf_rn(w3[j], ybuf2[L][j], a);
    out[r0 + L] = a;
  }
}

extern "C" void kernel_launch(void* const* d_in, const int* in_sizes, int n_in,
                              void* d_out, int out_size, void* d_ws, size_t ws_size,
                              hipStream_t stream) {
  const float* x    = (const float*)d_in[0];
  const float* w_ih = (const float*)d_in[1];
  const float* w_hh = (const float*)d_in[2];
  const float* b_ih = (const float*)d_in[3];
  const float* b_hh = (const float*)d_in[4];
  const float* w1   = (const float*)d_in[5];
  const float* b1   = (const float*)d_in[6];
  const float* w2   = (const float*)d_in[7];
  const float* b2   = (const float*)d_in[8];
  const float* w3   = (const float*)d_in[9];
  const float* b3   = (const float*)d_in[10];
  float* out = (float*)d_out;

  dim3 grid(BATCH / ROWS);  // 512 blocks -> 2 per CU
  dim3 block(THREADS);
  hipLaunchKernelGGL(gru_mfma, grid, block, 0, stream,
                     x, w_ih, w_hh, b_ih, b_hh, w1, b1, w2, b2, w3, b3, out);
}

// Round 5
// 663.570 us; speedup vs baseline: 1.5504x; 1.5504x over previous
//
#include <hip/hip_runtime.h>

// GRU_43387759624777 — Round 5: single-barrier step, gates in D-register layout.
//
// R4 post-mortem: bottleneck is the serial per-step chain (barrier, LDS, MFMA,
// gbuf round-trip, barrier, gates). Fix: wave wv owns tiles {wv,4+wv,8+wv} =
// all 3 gates of unit block 16wv..16wv+15, so after MFMA each lane holds
// r,z,n for (unit u, rows 4q..4q+3) in registers -> gate math directly on D
// fragments; gbuf + its bank conflicts + one barrier eliminated. h hi/lo bf16
// packed into one u32/word, written to a DOUBLE-BUFFERED A-frag buffer
// (read buf s&1, write s&1^1) -> one __syncthreads per step.
//
// Verified invariants (R3, absmax~0): A/B-frag [dim0=lane&15][k=(lane>>4)*8+j];
// C/D col=lane&15, row=(lane>>4)*4+reg; split-bf16 Whi*hhi + Whi*hlo + Wlo*hhi.
// hfrag word = hi | (lo<<16); 12-word row stride (16B-aligned, banks covered).

#define HID 64
#define SEQ 1024
#define BATCH 4096
#define ROWS 16
#define THREADS 256

typedef __attribute__((ext_vector_type(8))) short short8;
typedef __attribute__((ext_vector_type(4))) float f32x4;
typedef __attribute__((ext_vector_type(4))) unsigned uint4v;

#define SEL_HI 0x05040100u  // pack low halves of (w0,w1)
#define SEL_LO 0x07060302u  // pack high halves of (w0,w1)

union FragU { uint4v u; short8 s; };

__device__ __forceinline__ short f2bf(float f) {
  unsigned u = __float_as_uint(f);
  u += 0x7fffu + ((u >> 16) & 1u);   // RNE
  return (short)(u >> 16);
}
__device__ __forceinline__ float bf2f(short s) {
  return __uint_as_float(((unsigned)(unsigned short)s) << 16);
}
__device__ __forceinline__ float rcp_fast(float x) { return __builtin_amdgcn_rcpf(x); }

__global__ __launch_bounds__(THREADS, 1) void gru_mfma(
    const float* __restrict__ x,     // [B, T]
    const float* __restrict__ w_ih,  // [192, 1]
    const float* __restrict__ w_hh,  // [192, 64]
    const float* __restrict__ b_ih,  // [192]
    const float* __restrict__ b_hh,  // [192]
    const float* __restrict__ w1,    // [32, 64]
    const float* __restrict__ b1,    // [32]
    const float* __restrict__ w2,    // [16, 32]
    const float* __restrict__ b2,    // [16]
    const float* __restrict__ w3,    // [1, 16]
    const float* __restrict__ b3,    // [1]
    float* __restrict__ out)         // [B, 1]
{
  const int L  = threadIdx.x;        // 0..255
  const int l  = L & 63;             // lane in wave
  const int wv = L >> 6;             // wave 0..3
  const int r0 = blockIdx.x * ROWS;  // first batch row

  // ---------------- LDS ----------------
  // hfrag[buf][kt][fraglane][j] ; j 0..7 used, stride 12 words (16B-aligned rows,
  // 12l covers banks with only lanes l/l+8 aliasing = 2-way = free). 12 KB.
  __shared__ __align__(16) unsigned hfrag[2][2][64][12];
  __shared__ float xbuf[ROWS][68];   // x chunk; reused for h before MLP head
  __shared__ float ybuf1[ROWS][36];
  __shared__ float ybuf2[ROWS][20];

  // ---------------- W fragments (registers, once) ----------------
  // Wave wv owns tiles ntg = gate*4 + wv (gate=0,1,2): w_hh rows gate*64 + u.
  // B-frag: lane holds w_hh[ntg*16 + (l&15)][kt*32 + (l>>4)*8 + j].
  short8 bhi[3][2], blo[3][2];
  {
    const int n0 = l & 15, q = l >> 4;
    #pragma unroll
    for (int gate = 0; gate < 3; ++gate) {
      const int c = (gate * 4 + wv) * 16 + n0;   // = gate*64 + wv*16 + n0
      #pragma unroll
      for (int kt = 0; kt < 2; ++kt) {
        const float* p = w_hh + c * HID + kt * 32 + q * 8;
        f32x4 p0 = *(const f32x4*)p;
        f32x4 p1 = *(const f32x4*)(p + 4);
        float vals[8] = {p0[0], p0[1], p0[2], p0[3], p1[0], p1[1], p1[2], p1[3]};
        short8 hi8, lo8;
        #pragma unroll
        for (int j = 0; j < 8; ++j) {
          short h8 = f2bf(vals[j]);
          hi8[j] = h8;
          lo8[j] = f2bf(vals[j] - bf2f(h8));
        }
        bhi[gate][kt] = hi8;
        blo[gate][kt] = lo8;
      }
    }
  }

  // ---------------- per-lane elementwise constants ----------------
  // Lane owns unit u = 16*wv + (l&15), rows 4q..4q+3 (q = l>>4).
  const int u  = 16 * wv + (l & 15);
  const int qq = l >> 4;
  const float wir = w_ih[u], wiz = w_ih[64 + u], win = w_ih[128 + u];
  const float br  = b_ih[u] + b_hh[u];
  const float bz  = b_ih[64 + u] + b_hh[64 + u];
  const float bni = b_ih[128 + u];
  const float bnh = b_hh[128 + u];
  float h[4] = {0.f, 0.f, 0.f, 0.f};

  // h write target constants: value (row m, unit u) lives at
  // hfrag[buf][u>>5][m + 16*((u>>3)&3)][u&7], m = 4*qq + r.
  const int wkt = u >> 5;
  const int wQ  = (u >> 3) & 3;
  const int wj  = u & 7;

  // zero hfrag (h0 = 0; zero both buffers)
  for (int i = L; i < 2 * 2 * 64 * 12; i += THREADS) ((unsigned*)hfrag)[i] = 0u;

  const float* xblk = x + (size_t)r0 * SEQ;

  // ---------------- scan ----------------
  for (int tb = 0; tb < SEQ / 64; ++tb) {
    __syncthreads();  // prior xbuf reads complete
    {
      const int row = L >> 4, tq = L & 15;   // 16 rows x 16 quads
      f32x4 v = *(const f32x4*)(xblk + (size_t)row * SEQ + tb * 64 + tq * 4);
      *(f32x4*)&xbuf[row][tq * 4] = v;
    }
    #pragma unroll 2
    for (int s = 0; s < 64; ++s) {
      const int cur = s & 1, nxt = cur ^ 1;
      __syncthreads();  // prev step's hfrag writes + xbuf staging visible

      // ---- A-fragments: read packed words, unpack hi/lo via v_perm ----
      uint4v k0a = *(const uint4v*)&hfrag[cur][0][l][0];
      uint4v k0b = *(const uint4v*)&hfrag[cur][0][l][4];
      uint4v k1a = *(const uint4v*)&hfrag[cur][1][l][0];
      uint4v k1b = *(const uint4v*)&hfrag[cur][1][l][4];
      FragU ahi0, alo0, ahi1, alo1;
      #pragma unroll
      for (int p = 0; p < 2; ++p) {
        ahi0.u[p]     = __builtin_amdgcn_perm(k0a[2*p+1], k0a[2*p], SEL_HI);
        alo0.u[p]     = __builtin_amdgcn_perm(k0a[2*p+1], k0a[2*p], SEL_LO);
        ahi0.u[p + 2] = __builtin_amdgcn_perm(k0b[2*p+1], k0b[2*p], SEL_HI);
        alo0.u[p + 2] = __builtin_amdgcn_perm(k0b[2*p+1], k0b[2*p], SEL_LO);
        ahi1.u[p]     = __builtin_amdgcn_perm(k1a[2*p+1], k1a[2*p], SEL_HI);
        alo1.u[p]     = __builtin_amdgcn_perm(k1a[2*p+1], k1a[2*p], SEL_LO);
        ahi1.u[p + 2] = __builtin_amdgcn_perm(k1b[2*p+1], k1b[2*p], SEL_HI);
        alo1.u[p + 2] = __builtin_amdgcn_perm(k1b[2*p+1], k1b[2*p], SEL_LO);
      }

      // ---- MFMA: 3 gates, split-bf16 3 terms x K=64 ----
      f32x4 acc[3];
      #pragma unroll
      for (int gate = 0; gate < 3; ++gate) {
        f32x4 a = {0.f, 0.f, 0.f, 0.f};
        a = __builtin_amdgcn_mfma_f32_16x16x32_bf16(ahi0.s, bhi[gate][0], a, 0, 0, 0);
        a = __builtin_amdgcn_mfma_f32_16x16x32_bf16(ahi1.s, bhi[gate][1], a, 0, 0, 0);
        a = __builtin_amdgcn_mfma_f32_16x16x32_bf16(alo0.s, bhi[gate][0], a, 0, 0, 0);
        a = __builtin_amdgcn_mfma_f32_16x16x32_bf16(alo1.s, bhi[gate][1], a, 0, 0, 0);
        a = __builtin_amdgcn_mfma_f32_16x16x32_bf16(ahi0.s, blo[gate][0], a, 0, 0, 0);
        a = __builtin_amdgcn_mfma_f32_16x16x32_bf16(ahi1.s, blo[gate][1], a, 0, 0, 0);
        acc[gate] = a;
      }

      // ---- gates + h update directly on D layout (row 4qq+r, unit u) ----
      #pragma unroll
      for (int r = 0; r < 4; ++r) {
        const float xt = xbuf[4 * qq + r][s];   // broadcast within quad group
        float rpre = acc[0][r] + __fmaf_rn(xt, wir, br);
        float rr   = rcp_fast(1.0f + __expf(-rpre));
        float zpre = acc[1][r] + __fmaf_rn(xt, wiz, bz);
        float zz   = rcp_fast(1.0f + __expf(-zpre));
        float npre = __fmaf_rn(rr, acc[2][r] + bnh, __fmaf_rn(xt, win, bni));
        float nn   = 1.0f - 2.0f * rcp_fast(__expf(2.0f * npre) + 1.0f);
        h[r] = __fmaf_rn(zz, h[r] - nn, nn);
        unsigned hi = (unsigned)(unsigned short)f2bf(h[r]);
        unsigned lo = (unsigned)(unsigned short)f2bf(h[r] - bf2f((short)hi));
        hfrag[nxt][wkt][16 * wQ + 4 * qq + r][wj] = hi | (lo << 16);
      }
    }
  }

  // ---------------- MLP head: 64 -> 32 -> 16 -> 1 ----------------
  __syncthreads();
  #pragma unroll
  for (int r = 0; r < 4; ++r) xbuf[4 * qq + r][u] = h[r];  // h fp32 -> LDS
  __syncthreads();

  #pragma unroll
  for (int rep = 0; rep < 2; ++rep) {           // 16 rows x 32 outs = 512 tasks
    const int o = (L & 15) + 16 * rep;
    const int row = L >> 4;
    float a = b1[o];
    #pragma unroll
    for (int j4 = 0; j4 < 16; ++j4) {
      f32x4 wv4 = *(const f32x4*)&w1[o * 64 + 4 * j4];
      f32x4 hv  = *(const f32x4*)&xbuf[row][4 * j4];
      a += wv4[0] * hv[0] + wv4[1] * hv[1] + wv4[2] * hv[2] + wv4[3] * hv[3];
    }
    ybuf1[row][o] = (a > 0.0f) ? a : 0.01f * a;
  }
  __syncthreads();

  {
    const int o = L & 15;
    const int row = L >> 4;
    float a = b2[o];
    #pragma unroll
    for (int j4 = 0; j4 < 8; ++j4) {
      f32x4 wv4 = *(const f32x4*)&w2[o * 32 + 4 * j4];
      f32x4 yv  = *(const f32x4*)&ybuf1[row][4 * j4];
      a += wv4[0] * yv[0] + wv4[1] * yv[1] + wv4[2] * yv[2] + wv4[3] * yv[3];
    }
    ybuf2[row][o] = (a > 0.0f) ? a : 0.01f * a;
  }
  __syncthreads();

  if (L < ROWS) {
    float a = b3[0];
    #pragma unroll
    for (int j = 0; j < 16; ++j) a = __fmaf_rn(w3[j], ybuf2[L][j], a);
    out[r0 + L] = a;
  }
}

extern "C" void kernel_launch(void* const* d_in, const int* in_sizes, int n_in,
                              void* d_out, int out_size, void* d_ws, size_t ws_size,
                              hipStream_t stream) {
  const float* x    = (const float*)d_in[0];
  const float* w_ih = (const float*)d_in[1];
  const float* w_hh = (const float*)d_in[2];
  const float* b_ih = (const float*)d_in[3];
  const float* b_hh = (const float*)d_in[4];
  const float* w1   = (const float*)d_in[5];
  const float* b1   = (const float*)d_in[6];
  const float* w2   = (const float*)d_in[7];
  const float* b2   = (const float*)d_in[8];
  const float* w3   = (const float*)d_in[9];
  const float* b3   = (const float*)d_in[10];
  float* out = (float*)d_out;

  dim3 grid(BATCH / ROWS);  // 256 blocks -> 1 per CU
  dim3 block(THREADS);
  hipLaunchKernelGGL(gru_mfma, grid, block, 0, stream,
                     x, w_ih, w_hh, b_ih, b_hh, w1, b1, w2, b2, w3, b3, out);
}